// Round 9
// baseline (389.061 us; speedup 1.0000x reference)
//
#include <hip/hip_runtime.h>
#include <stdint.h>

#define N_TOK 2048
#define DDIM 1024
#define HDIM 4096
#define NEXP 8
#define MAXT64 40              // max 64-row tiles: worst case 32+7 = 39

// ctrl block layout (int offsets into d_ws)
#define C_COUNTS 0
#define C_CURSOR 8
#define C_PADOFF 16
#define C_TILECNT 24
#define C_TILE_E 32            // 48 slots
#define C_TILE_M0 80           // 48 slots
#define C_TILE_ROWS 128        // 48 slots
#define C_EXPERT 192           // 2048
#define C_PERM 2304            // 2560 slots

// workspace layout (bf16 weights path)
#define ACAPB 2304
#define XGB_OFF 32768
#define HGB_OFF (XGB_OFF + ACAPB*DDIM*2)
#define W1B_OFF (HGB_OFF + ACAPB*HDIM*2)
#define W2B_OFF (W1B_OFF + (size_t)NEXP*DDIM*HDIM*2)

#define G1B 640                // gemm1 blocks inside the fused dispatch
#define WC2B (NEXP*(HDIM/64)*(DDIM/64))   // 8192 wconv2 tiles

typedef float f32x4 __attribute__((ext_vector_type(4)));
typedef short s16x8 __attribute__((ext_vector_type(8)));
typedef unsigned int u32;
typedef u32 u32x2 __attribute__((ext_vector_type(2)));
typedef unsigned short u16;

__device__ __forceinline__ u16 f2bf(float f){
  u32 u = __float_as_uint(f);
  u += 0x7fffu + ((u >> 16) & 1u);   // RNE
  return (u16)(u >> 16);
}

__device__ __forceinline__ u32 pkbf(float a, float b){   // {lo16=bf(a), hi16=bf(b)}
  u32 r; asm("v_cvt_pk_bf16_f32 %0, %1, %2" : "=v"(r) : "v"(a), "v"(b)); return r;
}

// ---------------- gating: fp32 logits, argmax (first-max tie rule), counts ---
__global__ __launch_bounds__(256) void gate_kern(
    const float* __restrict__ x, const float* __restrict__ gw,
    const float* __restrict__ gb, int* __restrict__ ctrl)
{
  const int wv = threadIdx.x >> 6, l = threadIdx.x & 63;
  const int n = blockIdx.x * 4 + wv;            // one wave per token
  const float* xr = x + (size_t)n * DDIM;
  float acc[NEXP];
  #pragma unroll
  for (int e = 0; e < NEXP; e++) acc[e] = 0.f;
  #pragma unroll 4
  for (int i = 0; i < DDIM/64; i++){
    int k = i*64 + l;
    float xv = xr[k];
    const float* g = gw + (size_t)k * NEXP;
    #pragma unroll
    for (int e = 0; e < NEXP; e++) acc[e] = fmaf(xv, g[e], acc[e]);
  }
  #pragma unroll
  for (int e = 0; e < NEXP; e++){
    #pragma unroll
    for (int off = 32; off > 0; off >>= 1) acc[e] += __shfl_xor(acc[e], off);
  }
  if (l == 0){
    float best = acc[0] + gb[0]; int bi = 0;
    #pragma unroll
    for (int e = 1; e < NEXP; e++){
      float v = acc[e] + gb[e];
      if (v > best){ best = v; bi = e; }        // strict > keeps first index
    }
    ctrl[C_EXPERT + n] = bi;
    atomicAdd(&ctrl[C_COUNTS + bi], 1);
  }
}

// ------------- setup: aux loss, offsets (tight pack), 64-row tile table ------
__global__ void setup_kern(int* __restrict__ ctrl, float* __restrict__ aux_out)
{
  const int t = threadIdx.x;
  for (int i = t; i < 2560; i += 256) ctrl[C_PERM + i] = -1;
  if (t == 0){
    int off = 0, tc = 0;
    float aux = 0.f;
    for (int e = 0; e < NEXP; e++){
      int c = ctrl[C_COUNTS + e];
      ctrl[C_PADOFF + e] = off;
      ctrl[C_CURSOR + e] = off;
      int nt = (c + 63) / 64;
      for (int j = 0; j < nt; j++){
        ctrl[C_TILE_E   + tc] = e;
        ctrl[C_TILE_M0  + tc] = off + j*64;
        ctrl[C_TILE_ROWS+ tc] = min(64, c - j*64);
        tc++;
      }
      off += c;                                  // tight packing, no padding
      float fr = (float)c * (1.f/(float)N_TOK);
      float d = fr - 1.f/(float)NEXP;
      aux += d*d;
    }
    ctrl[C_TILECNT] = tc;
    *aux_out = aux * (1.f/(float)NEXP);
  }
}

// ------------------------- scatter tokens into grouped slots -----------------
__global__ __launch_bounds__(256) void scatter_kern(int* __restrict__ ctrl)
{
  const int n = blockIdx.x * 256 + threadIdx.x;
  const int e = ctrl[C_EXPERT + n];
  const int pos = atomicAdd(&ctrl[C_CURSOR + e], 1);
  ctrl[C_PERM + pos] = n;
}

// ------------------ gather + f32->bf16 convert of x into Xg ------------------
__global__ __launch_bounds__(256) void xg_kern(
    const float* __restrict__ x, const int* __restrict__ ctrl,
    u16* __restrict__ Xg)
{
  const int slot = blockIdx.x, t = threadIdx.x;
  const int tok = ctrl[C_PERM + slot];
  ushort4 o;
  if (tok >= 0){
    f32x4 v = *(const f32x4*)(x + (size_t)tok*DDIM + t*4);
    o.x = f2bf(v.x); o.y = f2bf(v.y); o.z = f2bf(v.z); o.w = f2bf(v.w);
  } else { o.x = 0; o.y = 0; o.z = 0; o.w = 0; }
  *(ushort4*)(Xg + (size_t)slot*DDIM + t*4) = o;
}

// ---------------- W transpose-convert body (device) --------------------------
// [E][K][NN] f32 -> [E][NN][K] bf16 ; 64x64 tiles via padded LDS.
__device__ __forceinline__ void wconv_body(
    int b, const float* __restrict__ src, u16* __restrict__ dst,
    int K, int NN, float (*ld)[67], int t)
{
  const int TN = NN >> 6, TK = K >> 6;
  const int e  = b / (TK*TN); b -= e*TK*TN;
  const int kt = b / TN;
  const int nt = b - kt*TN;

  const float* S = src + (size_t)e*K*NN + (size_t)(kt*64)*NN + nt*64;
  #pragma unroll
  for (int p = 0; p < 4; p++){
    int kr = p*16 + (t >> 4);
    int nc = (t & 15) * 4;
    f32x4 v = *(const f32x4*)(S + (size_t)kr*NN + nc);
    ld[kr][nc+0] = v.x; ld[kr][nc+1] = v.y; ld[kr][nc+2] = v.z; ld[kr][nc+3] = v.w;
  }
  __syncthreads();

  u16* D = dst + (size_t)e*NN*K + (size_t)(nt*64)*K + kt*64;
  #pragma unroll
  for (int q = 0; q < 2; q++){
    int s = q*256 + t;
    int n = s >> 3, kc = s & 7;
    union { u32 u[4]; } o;
    #pragma unroll
    for (int j = 0; j < 4; j++)
      o.u[j] = pkbf(ld[kc*8 + 2*j][n], ld[kc*8 + 2*j + 1][n]);
    *(u32x2*)(D + (size_t)n*K + kc*8)     = (u32x2){o.u[0], o.u[1]};
    *(u32x2*)(D + (size_t)n*K + kc*8 + 4) = (u32x2){o.u[2], o.u[3]};
  }
}

__global__ __launch_bounds__(256) void wconv_kern(
    const float* __restrict__ src, u16* __restrict__ dst, int K, int NN)
{
  __shared__ float ld[64][67];
  wconv_body(blockIdx.x, src, dst, K, NN, ld, threadIdx.x);
}

// ----------------- wave-independent GEMM body (no LDS, no barriers) ----------
// One 64x64 tile per wave; k-PAIR fragment loads: each phase reads a full
// 128B line per row (two adjacent 16B/lane dwordx4) -> no L2 sector waste
// (R8's 187MB -> ~105MB). Register double-buffer, no vmcnt(0) drain ever.
template<int MODE>
__device__ __forceinline__ void gemm_wave(
    int bid, const u16* __restrict__ Ag, const u16* __restrict__ Wt,
    const float* __restrict__ bias, u16* __restrict__ Hg,
    float* __restrict__ outp, const int* __restrict__ ctrl, int tid)
{
  constexpr int K    = (MODE==1) ? DDIM : HDIM;
  constexpr int NN   = (MODE==1) ? HDIM : DDIM;
  constexpr int KS   = (MODE==1) ? 1 : 4;
  constexpr int KLOC = K / KS;                 // 1024
  constexpr int NPH  = KLOC / 64;              // 16 phases (64 k each)

  // XCD-chunk swizzle over the 640-block gemm range (640%8==0, bijective)
  const int cpx = G1B >> 3;
  const int bsw = (bid & 7) * cpx + (bid >> 3);
  const int wwid = bsw*4 + (tid >> 6);

  const int mt  = wwid % MAXT64;
  const int nks = wwid / MAXT64;
  if (mt >= ctrl[C_TILECNT]) return;
  const int nt = (KS==1) ? nks : (nks >> 2);
  const int ks = (KS==1) ? 0   : (nks & 3);

  const int e    = ctrl[C_TILE_E + mt];
  const int m0   = ctrl[C_TILE_M0 + mt];
  const int rows = ctrl[C_TILE_ROWS + mt];
  const int n0   = nt * 64;
  const int kb   = ks * KLOC;

  const int l = tid & 63;
  const int lhi = l >> 4, llo = l & 15;

  f32x4 acc[4][4];
  #pragma unroll
  for (int mf = 0; mf < 4; mf++)
    #pragma unroll
    for (int nf = 0; nf < 4; nf++) acc[mf][nf] = (f32x4){0.f,0.f,0.f,0.f};

  const u16* Ap = Ag + (size_t)(m0 + llo)*K + lhi*8 + kb;
  const u16* Bp = Wt + (size_t)e*NN*K + (size_t)(n0 + llo)*K + lhi*8 + kb;

  s16x8 a0[4][2], b0[4][2], a1[4][2], b1[4][2];

#define LOADP(AF, BF, ko) { \
    _Pragma("unroll") \
    for (int mf = 0; mf < 4; mf++){ \
      AF[mf][0] = *(const s16x8*)(Ap + (size_t)mf*16*K + (ko)); \
      AF[mf][1] = *(const s16x8*)(Ap + (size_t)mf*16*K + (ko) + 32); } \
    _Pragma("unroll") \
    for (int nf = 0; nf < 4; nf++){ \
      BF[nf][0] = *(const s16x8*)(Bp + (size_t)nf*16*K + (ko)); \
      BF[nf][1] = *(const s16x8*)(Bp + (size_t)nf*16*K + (ko) + 32); } }

#define MFP(AF, BF) { \
    _Pragma("unroll") \
    for (int h = 0; h < 2; h++) \
      _Pragma("unroll") \
      for (int mf = 0; mf < 4; mf++) \
        _Pragma("unroll") \
        for (int nf = 0; nf < 4; nf++) \
          acc[mf][nf] = __builtin_amdgcn_mfma_f32_16x16x32_bf16(AF[mf][h], BF[nf][h], acc[mf][nf], 0, 0, 0); }

  LOADP(a0, b0, 0);
  #pragma unroll 1
  for (int ph = 0; ph < NPH; ph += 2){
    if (ph+1 < NPH){ LOADP(a1, b1, (ph+1)*64); }
    MFP(a0, b0);
    if (ph+2 < NPH){ LOADP(a0, b0, (ph+2)*64); }
    if (ph+1 < NPH){ MFP(a1, b1); }
  }

  if constexpr (MODE == 1){
    const float* bp = bias + (size_t)e*NN + n0;
    #pragma unroll
    for (int nf = 0; nf < 4; nf++){
      const int cl = nf*16 + llo;
      const float bb = bp[cl];
      #pragma unroll
      for (int mf = 0; mf < 4; mf++){
        #pragma unroll
        for (int r = 0; r < 4; r++){
          const int rl = mf*16 + lhi*4 + r;
          if (rl < rows){
            float vv = acc[mf][nf][r] + bb;
            float gel = 0.5f * vv * (1.0f + erff(vv * 0.70710678118f)); // exact gelu
            Hg[(size_t)(m0+rl)*NN + n0 + cl] = f2bf(gel);
          }
        }
      }
    }
  } else {
    const float* bp = bias + (size_t)e*NN + n0;
    const bool addb = (ks == 0);
    #pragma unroll
    for (int mf = 0; mf < 4; mf++){
      #pragma unroll
      for (int r = 0; r < 4; r++){
        const int rl = mf*16 + lhi*4 + r;
        if (rl < rows){
          const int tok = ctrl[C_PERM + m0 + rl];
          #pragma unroll
          for (int nf = 0; nf < 4; nf++){
            const int cl = nf*16 + llo;
            float v = acc[mf][nf][r] + (addb ? bp[cl] : 0.f);
            atomicAdd(&outp[(size_t)tok*DDIM + n0 + cl], v);
          }
        }
      }
    }
  }
#undef LOADP
#undef MFP
}

// ------------- fused dispatch: gemm1 (blocks 0..G1B-1)  ||  wconv2 -----------
// Independent work co-resident: gemm1's ~2 TB/s leaves fabric headroom that
// wconv2's 4.2 TB/s streaming soaks up (R7/R8 measured rates).
__global__ __launch_bounds__(256) void fused1_kern(
    const u16* __restrict__ Xg, const u16* __restrict__ W1b,
    const float* __restrict__ b1, u16* __restrict__ Hg,
    const int* __restrict__ ctrl,
    const float* __restrict__ w2, u16* __restrict__ W2b)
{
  __shared__ float ld[64][67];
  if (blockIdx.x < G1B){
    gemm_wave<1>(blockIdx.x, Xg, W1b, b1, Hg, nullptr, ctrl, threadIdx.x);
  } else {
    wconv_body(blockIdx.x - G1B, w2, W2b, HDIM, DDIM, ld, threadIdx.x);
  }
}

__global__ __launch_bounds__(256, 2) void gemm2_kern(
    const u16* __restrict__ Hg, const u16* __restrict__ W2b,
    const float* __restrict__ b2, float* __restrict__ outp,
    const int* __restrict__ ctrl)
{
  gemm_wave<2>(blockIdx.x, Hg, W2b, b2, nullptr, outp, ctrl, threadIdx.x);
}

extern "C" void kernel_launch(void* const* d_in, const int* in_sizes, int n_in,
                              void* d_out, int out_size, void* d_ws, size_t ws_size,
                              hipStream_t stream)
{
  (void)in_sizes; (void)n_in; (void)out_size; (void)ws_size;
  const float* x  = (const float*)d_in[0];
  const float* gw = (const float*)d_in[1];
  const float* gb = (const float*)d_in[2];
  const float* w1 = (const float*)d_in[3];
  const float* b1 = (const float*)d_in[4];
  const float* w2 = (const float*)d_in[5];
  const float* b2 = (const float*)d_in[6];
  float* out = (float*)d_out;
  char* ws = (char*)d_ws;
  int* ctrl = (int*)ws;
  u16* Xg  = (u16*)(ws + XGB_OFF);
  u16* Hg  = (u16*)(ws + HGB_OFF);
  u16* W1b = (u16*)(ws + W1B_OFF);
  u16* W2b = (u16*)(ws + W2B_OFF);

  hipMemsetAsync(ctrl, 0, 64, stream);                       // counts
  hipMemsetAsync(out, 0, (size_t)N_TOK*DDIM*4, stream);      // split-K accum base
  gate_kern<<<N_TOK/4, 256, 0, stream>>>(x, gw, gb, ctrl);
  setup_kern<<<1, 256, 0, stream>>>(ctrl, out + (size_t)N_TOK*DDIM);
  scatter_kern<<<N_TOK/256, 256, 0, stream>>>(ctrl);
  xg_kern<<<N_TOK, 256, 0, stream>>>(x, ctrl, Xg);

  // W1 convert, then {gemm1 || W2 convert}, then gemm2
  wconv_kern<<<NEXP*(DDIM/64)*(HDIM/64), 256, 0, stream>>>(w1, W1b, DDIM, HDIM);
  fused1_kern<<<G1B + WC2B, 256, 0, stream>>>(Xg, W1b, b1, Hg, ctrl, w2, W2b);
  gemm2_kern<<<G1B, 256, 0, stream>>>(Hg, W2b, b2, out, ctrl);
}

// Round 10
// 268.910 us; speedup vs baseline: 1.4468x; 1.4468x over previous
//
#include <hip/hip_runtime.h>
#include <stdint.h>

#define N_TOK 2048
#define DDIM 1024
#define HDIM 4096
#define NEXP 8
#define MAXT 24                // ceil-sum of per-expert tiles at BM=128: <= 8+16

// ctrl block layout (int offsets into d_ws)
#define C_COUNTS 0
#define C_CURSOR 8
#define C_PADOFF 16
#define C_TILECNT 24
#define C_TILE_E 32            // 48 slots
#define C_TILE_M0 80           // 48 slots
#define C_TILE_ROWS 128        // 48 slots
#define C_EXPERT 192           // 2048
#define C_PERM 2304            // 2560 slots

// workspace layout
#define ACAPB 2304             // Xg/Hg rows: 2048 + tile overrun (max 2175)
#define XGB_OFF 32768
#define HGB_OFF (XGB_OFF + ACAPB*DDIM*2)

typedef float f32x4 __attribute__((ext_vector_type(4)));
typedef short s16x8 __attribute__((ext_vector_type(8)));
typedef unsigned int u32;
typedef unsigned short u16;

__device__ __forceinline__ u16 f2bf(float f){
  u32 u = __float_as_uint(f);
  u += 0x7fffu + ((u >> 16) & 1u);   // RNE
  return (u16)(u >> 16);
}

__device__ __forceinline__ u32 pkbf(float a, float b){   // {lo16=bf(a), hi16=bf(b)}
  u32 r; asm("v_cvt_pk_bf16_f32 %0, %1, %2" : "=v"(r) : "v"(a), "v"(b)); return r;
}

__device__ __forceinline__ void gl_lds16(const void* g, void* l){
  __builtin_amdgcn_global_load_lds((const __attribute__((address_space(1))) u32*)g,
                                   (__attribute__((address_space(3))) u32*)l, 16, 0, 0);
}

// ---------------- gating: fp32 logits, argmax (first-max tie rule), counts ---
__global__ __launch_bounds__(256) void gate_kern(
    const float* __restrict__ x, const float* __restrict__ gw,
    const float* __restrict__ gb, int* __restrict__ ctrl)
{
  const int wv = threadIdx.x >> 6, l = threadIdx.x & 63;
  const int n = blockIdx.x * 4 + wv;            // one wave per token
  const float* xr = x + (size_t)n * DDIM;
  float acc[NEXP];
  #pragma unroll
  for (int e = 0; e < NEXP; e++) acc[e] = 0.f;
  #pragma unroll 4
  for (int i = 0; i < DDIM/64; i++){
    int k = i*64 + l;
    float xv = xr[k];
    const float* g = gw + (size_t)k * NEXP;
    #pragma unroll
    for (int e = 0; e < NEXP; e++) acc[e] = fmaf(xv, g[e], acc[e]);
  }
  #pragma unroll
  for (int e = 0; e < NEXP; e++){
    #pragma unroll
    for (int off = 32; off > 0; off >>= 1) acc[e] += __shfl_xor(acc[e], off);
  }
  if (l == 0){
    float best = acc[0] + gb[0]; int bi = 0;
    #pragma unroll
    for (int e = 1; e < NEXP; e++){
      float v = acc[e] + gb[e];
      if (v > best){ best = v; bi = e; }        // strict > keeps first index
    }
    ctrl[C_EXPERT + n] = bi;
    atomicAdd(&ctrl[C_COUNTS + bi], 1);
  }
}

// ------------- setup: aux loss, offsets (tight pack), 128-row tile table -----
__global__ void setup_kern(int* __restrict__ ctrl, float* __restrict__ aux_out)
{
  const int t = threadIdx.x;
  for (int i = t; i < 2560; i += 256) ctrl[C_PERM + i] = -1;
  if (t == 0){
    int off = 0, tc = 0;
    float aux = 0.f;
    for (int e = 0; e < NEXP; e++){
      int c = ctrl[C_COUNTS + e];
      ctrl[C_PADOFF + e] = off;
      ctrl[C_CURSOR + e] = off;
      int nt = (c + 127) / 128;
      for (int j = 0; j < nt; j++){
        ctrl[C_TILE_E   + tc] = e;
        ctrl[C_TILE_M0  + tc] = off + j*128;
        ctrl[C_TILE_ROWS+ tc] = min(128, c - j*128);
        tc++;
      }
      off += c;                                  // tight packing, no padding
      float fr = (float)c * (1.f/(float)N_TOK);
      float d = fr - 1.f/(float)NEXP;
      aux += d*d;
    }
    ctrl[C_TILECNT] = tc;
    *aux_out = aux * (1.f/(float)NEXP);
  }
}

// ------------------------- scatter tokens into grouped slots -----------------
__global__ __launch_bounds__(256) void scatter_kern(int* __restrict__ ctrl)
{
  const int n = blockIdx.x * 256 + threadIdx.x;
  const int e = ctrl[C_EXPERT + n];
  const int pos = atomicAdd(&ctrl[C_CURSOR + e], 1);
  ctrl[C_PERM + pos] = n;
}

// ------------------ gather + f32->bf16 convert of x into Xg ------------------
__global__ __launch_bounds__(256) void xg_kern(
    const float* __restrict__ x, const int* __restrict__ ctrl,
    u16* __restrict__ Xg)
{
  const int slot = blockIdx.x, t = threadIdx.x;
  const int tok = ctrl[C_PERM + slot];
  ushort4 o;
  if (tok >= 0){
    f32x4 v = *(const f32x4*)(x + (size_t)tok*DDIM + t*4);
    o.x = f2bf(v.x); o.y = f2bf(v.y); o.z = f2bf(v.z); o.w = f2bf(v.w);
  } else { o.x = 0; o.y = 0; o.z = 0; o.w = 0; }
  *(ushort4*)(Xg + (size_t)slot*DDIM + t*4) = o;
}

// ------------- producer/consumer FFN GEMMs (fp32 weights direct) -------------
// MODE 1: Hg = gelu(Xg @ w1[e] + b1[e])   K=1024, NN=4096
// MODE 2: out[tok] += Hg @ w2[e] + b2[e]  K=4096, NN=1024, split-K x4 + atomics
//
// 512 threads = 8 waves: waves 0-3 PRODUCE (glds-stage A bf16 + W fp32 for
// tile t+1, then drain), waves 4-7 CONSUME (R2-verified read-side transpose
// + cvt_pk + MFMA on tile t, 64x64 output each). The producer's vmcnt(0)
// drain (inside __syncthreads) overlaps the consumers' compute phase -- the
// stream never waits on MFMA and MFMA never waits on address issue. This is
// the wave-specialization escape from the measured ~1.3 TB/s drain-loop cap
// (R0/R2/R3/R6/R7 all capped; wconv streams 4.2 TB/s on the same chip).
// All swizzles verbatim from R2 (measured SQ_LDS_BANK_CONFLICT = 0).
template<int MODE>
__global__ __launch_bounds__(512, 4) void moe_gemm_pc(
    const u16* __restrict__ Ag, const float* __restrict__ W,
    const float* __restrict__ bias, u16* __restrict__ Hg,
    float* __restrict__ outp, const int* __restrict__ ctrl)
{
  constexpr int K    = (MODE==1) ? DDIM : HDIM;
  constexpr int NN   = (MODE==1) ? HDIM : DDIM;
  constexpr int KS   = (MODE==1) ? 1 : 4;
  constexpr int KLOC = K / KS;                  // 1024
  constexpr int BM   = 128;
  constexpr int BN   = 128;
  constexpr int BK   = 32;
  constexpr int NT   = KLOC / BK;               // 32

  const int by = blockIdx.y;
  if (by >= ctrl[C_TILECNT]) return;
  const int e    = ctrl[C_TILE_E + by];
  const int m0   = ctrl[C_TILE_M0 + by];
  const int rows = ctrl[C_TILE_ROWS + by];
  const int n0   = blockIdx.x * BN;
  const int kb   = (MODE==1) ? 0 : blockIdx.z * KLOC;

  const int tid = threadIdx.x;
  const int w = tid >> 6, l = tid & 63;
  const bool prod = (w < 4);
  const int lhi = l >> 4, llo = l & 15;

  __shared__ __align__(16) u16   As[2][BM*BK];   // bf16 A tile, 2 x 8 KB
  __shared__ __align__(16) float Bs[2][BK*BN];   // fp32 W tile, 2 x 16 KB
  __shared__ int perm_s[BM];

  if constexpr (MODE == 2){
    if (tid < BM) perm_s[tid] = ctrl[C_PERM + m0 + tid];
  }

  // ---- producer staging geometry (threads 0..255) ----
  const u16*   Abase = Ag + (size_t)m0 * K;
  const float* Wb    = W + (size_t)e * K * NN + n0;
  int arow[2], apos[2], brow[4], bpos[4];
  #pragma unroll
  for (int i = 0; i < 2; i++){
    int f = i*256 + tid;                 // A: 512 chunks of 16B (128 rows x 4)
    arow[i] = f >> 2;
    apos[i] = (f & 3) ^ (arow[i] & 3);   // R2 chunk-XOR (0 conflicts)
  }
  #pragma unroll
  for (int i = 0; i < 4; i++){
    int f = i*256 + tid;                 // B: 1024 chunks of 16B (32 rows x 32)
    brow[i] = f >> 5;
    bpos[i] = (f & 31) ^ (((brow[i] >> 3) & 1) << 2);   // R2 SWB
  }

  // ---- consumer geometry (threads 256..511) ----
  const int cw = w - 4;
  const int wr = cw >> 1, wc = cw & 1;   // 2x2 wave grid, 64x64 each
  const int col0 = wc*64 + llo;
  const int bswz = (lhi & 1) << 2;       // read-side swizzle (matches SWB)

  f32x4 acc[4][4];
  #pragma unroll
  for (int mf = 0; mf < 4; mf++)
    #pragma unroll
    for (int nf = 0; nf < 4; nf++) acc[mf][nf] = (f32x4){0.f,0.f,0.f,0.f};

#define STAGE(buf, k0) { \
    u16*   ad = &As[buf][(w*64)*8]; \
    float* bd = &Bs[buf][(w*64)*4]; \
    _Pragma("unroll") \
    for (int i = 0; i < 2; i++) \
      gl_lds16(Abase + (size_t)arow[i]*K + (k0) + apos[i]*8, ad + i*256*8); \
    _Pragma("unroll") \
    for (int i = 0; i < 4; i++) \
      gl_lds16(Wb + (size_t)((k0) + brow[i])*NN + bpos[i]*4, bd + i*256*4); }

#define COMPUTE(buf) { \
    s16x8 a[4]; \
    _Pragma("unroll") \
    for (int mf = 0; mf < 4; mf++){ \
      int row = wr*64 + mf*16 + llo; \
      int pos = lhi ^ (row & 3); \
      a[mf] = *(const s16x8*)&As[buf][row*BK + pos*8]; } \
    _Pragma("unroll") \
    for (int nf = 0; nf < 4; nf++){ \
      const int col = col0 + nf*16; \
      const float* bp_ = &Bs[buf][(lhi*8)*BN + \
                                  ((((col) >> 2) ^ bswz) << 2) + ((col) & 3)]; \
      union { u32 u[4]; s16x8 v; } bb_; \
      bb_.u[0] = pkbf(bp_[0*BN], bp_[1*BN]); \
      bb_.u[1] = pkbf(bp_[2*BN], bp_[3*BN]); \
      bb_.u[2] = pkbf(bp_[4*BN], bp_[5*BN]); \
      bb_.u[3] = pkbf(bp_[6*BN], bp_[7*BN]); \
      _Pragma("unroll") \
      for (int mf = 0; mf < 4; mf++) \
        acc[mf][nf] = __builtin_amdgcn_mfma_f32_16x16x32_bf16(a[mf], bb_.v, acc[mf][nf], 0, 0, 0); \
    } }

  // prologue: producers fill buffer 0; syncthreads drains their glds
  if (prod){ STAGE(0, kb); }
  __syncthreads();

  #pragma unroll 1
  for (int t = 0; t < NT; t++){
    if (prod){
      if (t+1 < NT){ STAGE((t+1)&1, kb + (t+1)*BK); }
      // this wave's syncthreads drain (vmcnt 0) overlaps consumers' COMPUTE(t)
    } else {
      COMPUTE(t&1);
    }
    __syncthreads();
  }

  if (!prod){
    if constexpr (MODE == 1){
      const float* bp = bias + (size_t)e*NN + n0;
      #pragma unroll
      for (int nf = 0; nf < 4; nf++){
        const int cl = wc*64 + nf*16 + llo;
        const float bb = bp[cl];
        #pragma unroll
        for (int mf = 0; mf < 4; mf++){
          #pragma unroll
          for (int r = 0; r < 4; r++){
            const int rl = wr*64 + mf*16 + lhi*4 + r;
            if (rl < rows){
              float vv = acc[mf][nf][r] + bb;
              float gel = 0.5f * vv * (1.0f + erff(vv * 0.70710678118f)); // exact gelu
              Hg[(size_t)(m0+rl)*NN + n0 + cl] = f2bf(gel);
            }
          }
        }
      }
    } else {
      const float* bp = bias + (size_t)e*NN + n0;
      const bool addb = (blockIdx.z == 0);
      #pragma unroll
      for (int mf = 0; mf < 4; mf++){
        #pragma unroll
        for (int r = 0; r < 4; r++){
          const int rl = wr*64 + mf*16 + lhi*4 + r;
          if (rl < rows){
            const int tok = perm_s[rl];
            #pragma unroll
            for (int nf = 0; nf < 4; nf++){
              const int cl = wc*64 + nf*16 + llo;
              float v = acc[mf][nf][r] + (addb ? bp[cl] : 0.f);
              atomicAdd(&outp[(size_t)tok*DDIM + n0 + cl], v);
            }
          }
        }
      }
    }
  }
#undef STAGE
#undef COMPUTE
}

extern "C" void kernel_launch(void* const* d_in, const int* in_sizes, int n_in,
                              void* d_out, int out_size, void* d_ws, size_t ws_size,
                              hipStream_t stream)
{
  (void)in_sizes; (void)n_in; (void)out_size; (void)ws_size;
  const float* x  = (const float*)d_in[0];
  const float* gw = (const float*)d_in[1];
  const float* gb = (const float*)d_in[2];
  const float* w1 = (const float*)d_in[3];
  const float* b1 = (const float*)d_in[4];
  const float* w2 = (const float*)d_in[5];
  const float* b2 = (const float*)d_in[6];
  float* out = (float*)d_out;
  char* ws = (char*)d_ws;
  int* ctrl = (int*)ws;
  u16* Xg = (u16*)(ws + XGB_OFF);
  u16* Hg = (u16*)(ws + HGB_OFF);

  hipMemsetAsync(ctrl, 0, 64, stream);                       // counts
  hipMemsetAsync(out, 0, (size_t)N_TOK*DDIM*4, stream);      // split-K accum base
  gate_kern<<<N_TOK/4, 256, 0, stream>>>(x, gw, gb, ctrl);
  setup_kern<<<1, 256, 0, stream>>>(ctrl, out + (size_t)N_TOK*DDIM);
  scatter_kern<<<N_TOK/256, 256, 0, stream>>>(ctrl);
  xg_kern<<<ACAPB, 256, 0, stream>>>(x, ctrl, Xg);

  moe_gemm_pc<1><<<dim3(HDIM/128, MAXT),    512, 0, stream>>>(Xg, w1, b1, Hg, nullptr, ctrl);
  moe_gemm_pc<2><<<dim3(DDIM/128, MAXT, 4), 512, 0, stream>>>(Hg, w2, b2, nullptr, out, ctrl);
}